// Round 7
// baseline (295.872 us; speedup 1.0000x reference)
//
#include <hip/hip_runtime.h>
#include <cmath>

#define S_LEN 2048
#define EMB   1024
#define NHEAD 16
#define DHEAD 64

typedef __attribute__((ext_vector_type(8))) short bf16x8;
typedef __attribute__((ext_vector_type(4))) float f32x4;

__device__ __forceinline__ unsigned short f2bf(float f){
    union { float f; unsigned u; } v; v.f = f;
    unsigned r = v.u + 0x7fffu + ((v.u >> 16) & 1u);
    return (unsigned short)(r >> 16);
}

__device__ __forceinline__ unsigned pk2bf(float a, float b){
#if __has_builtin(__builtin_amdgcn_cvt_pk_bf16_f32)
    typedef __attribute__((ext_vector_type(2))) __bf16 bf2;
    bf2 r = __builtin_amdgcn_cvt_pk_bf16_f32(a, b);
    return *(unsigned*)&r;
#else
    return (unsigned)f2bf(a) | ((unsigned)f2bf(b) << 16);
#endif
}

__device__ __forceinline__ float fast_exp2(float x){
#if __has_builtin(__builtin_amdgcn_exp2f)
    return __builtin_amdgcn_exp2f(x);
#else
    return exp2f(x);
#endif
}

__device__ __forceinline__ float fast_rcp(float x){
#if __has_builtin(__builtin_amdgcn_rcpf)
    return __builtin_amdgcn_rcpf(x);
#else
    return 1.0f / x;
#endif
}

// ---------------- fused prep: range-dispatched over blockIdx.x ----------------
// [0,4096):       Q -> bf16 [N,H,S,D] (prescaled exp2-domain); K -> FRAGMENT order
// [4096,5120):    V -> FRAGMENT order
// [5120,6144):    W -> bf16
// [6144,14336):   mask -> fragment-q pair-masks Mf[n][kslab=k>>4][q][pair(8 uints)]
//                 (flash reads lane(il,quad) at record(q=..+il)+quad*2 -> 512B contiguous)
// [14336,15376):  zero the Op+Lp atomic accumulators
__global__ void prep_all(const float* __restrict__ q, const float* __restrict__ k,
                         const float* __restrict__ v, const int* __restrict__ mask,
                         const float* __restrict__ W,
                         unsigned short* __restrict__ Qb, unsigned short* __restrict__ Kb,
                         unsigned short* __restrict__ Vt, unsigned short* __restrict__ Wb,
                         unsigned* __restrict__ Mf, float4* __restrict__ Zp){
    __shared__ unsigned short tile[64*68];
    const int b = blockIdx.x, tid = threadIdx.x;
    if (b < 4096){
        const float SC = 0.045084220027780106f;   // log2(e)/32
        int base = (b*256 + tid) * 4;
        int e = base & (EMB - 1);
        int s = (base >> 10) & (S_LEN - 1);
        int n = base >> 21;
        int h = e >> 6, d = e & 63;
        float4 qv = *(const float4*)(q + base);
        float4 kv = *(const float4*)(k + base);
        uint2 qp, kp;
        qp.x = pk2bf(qv.x*SC, qv.y*SC);
        qp.y = pk2bf(qv.z*SC, qv.w*SC);
        kp.x = pk2bf(kv.x, kv.y);
        kp.y = pk2bf(kv.z, kv.w);
        *(uint2*)(Qb + ((size_t)((n*NHEAD + h)*S_LEN + s))*DHEAD + d) = qp;
        int slab = s >> 4, sil = s & 15;
        int ks = d >> 5, qd = (d >> 3) & 3, j = d & 7;
        size_t koff = ((size_t)((n*NHEAD + h)*128 + slab))*1024 + ks*512 + (qd*16 + sil)*8 + j;
        *(uint2*)(Kb + koff) = kp;
    } else if (b < 5120){
        int idx = b - 4096;
        int st = idx & 31, h = (idx >> 5) & 15, n = idx >> 9;
        int sbase = st * 64;
#pragma unroll
        for (int i = 0; i < 4; i++){
            int c = tid + i*256;
            int srow = c >> 4, c4 = (c & 15) * 4;
            float4 x = *(const float4*)(v + (n*S_LEN + sbase + srow)*EMB + h*DHEAD + c4);
            uint2 p;
            p.x = pk2bf(x.x, x.y);
            p.y = pk2bf(x.z, x.w);
            *(uint2*)&tile[srow*68 + c4] = p;
        }
        __syncthreads();
        unsigned short* Vh = Vt + ((size_t)((n*NHEAD + h)*32 + st))*4096;
#pragma unroll
        for (int i = 0; i < 2; i++){
            int c = tid + i*256;            // 0..511 chunks of 16B
            int ln = c & 63, dk = c >> 6;   // dk = dt*2+kk
            int dt = dk >> 1, kk = dk & 1;
            int q2 = ln >> 4, i2 = ln & 15;
            int colb = dt*16 + i2;
            int rowb = kk*32 + q2*8;
            unsigned u0 = (unsigned)tile[(rowb+0)*68 + colb] | ((unsigned)tile[(rowb+1)*68 + colb] << 16);
            unsigned u1 = (unsigned)tile[(rowb+2)*68 + colb] | ((unsigned)tile[(rowb+3)*68 + colb] << 16);
            unsigned u2 = (unsigned)tile[(rowb+4)*68 + colb] | ((unsigned)tile[(rowb+5)*68 + colb] << 16);
            unsigned u3 = (unsigned)tile[(rowb+6)*68 + colb] | ((unsigned)tile[(rowb+7)*68 + colb] << 16);
            uint4 pk; pk.x = u0; pk.y = u1; pk.z = u2; pk.w = u3;
            *(uint4*)(Vh + c*8) = pk;
        }
    } else if (b < 6144){
        int base = ((b - 5120)*256 + tid) * 4;
        float4 x = *(const float4*)(W + base);
        uint2 p;
        p.x = pk2bf(x.x, x.y);
        p.y = pk2bf(x.z, x.w);
        *(uint2*)(Wb + base) = p;
    } else if (b < 14336){
        int u = (b - 6144)*256 + tid;                 // one int4 = 4 k-values
        int4 m = ((const int4*)mask)[u];
        int gk = u*4;
        int kk = gk & (S_LEN-1);
        int qq = (gk >> 11) & (S_LEN-1);
        int nn = gk >> 22;
        uint2 o;
        o.x = (m.x ? 0xFFFFu : 0u) | (m.y ? 0xFFFF0000u : 0u);
        o.y = (m.z ? 0xFFFFu : 0u) | (m.w ? 0xFFFF0000u : 0u);
        size_t dst = ((size_t)(nn*128 + (kk >> 4))*2048 + qq)*8 + ((kk & 15) >> 1);
        *(uint2*)(Mf + dst) = o;
    } else {
        int base = (b - 14336)*1024 + tid;            // float4 units
        float4 z = {0.f, 0.f, 0.f, 0.f};
#pragma unroll
        for (int i = 0; i < 4; i++)
            Zp[base + i*256] = z;
    }
}

// ---------------- flash attention v5: barrier-free, fragment-direct K/V/mask ----------------
// r6 structure (correct) with the mask scatter fixed: pair-masks now in fragment-q order,
// one uint2 load per (rt,t) spans 512 CONTIGUOUS bytes across the wave (was 64 x 4KB-strided
// 8B segments -> ~512 TA transactions/wave-iter, the invariant wall of r2-r6).
__global__ __launch_bounds__(256, 4) void flash_attn(
    const unsigned short* __restrict__ Qb, const unsigned short* __restrict__ Kfr,
    const unsigned short* __restrict__ Vfr, const unsigned* __restrict__ Mf,
    float* __restrict__ Op, float* __restrict__ Lp){
    __shared__ unsigned short Pt[4][32*64];

    const int n = blockIdx.z, qt = blockIdx.x;
    const int h = blockIdx.y & 15, split = blockIdx.y >> 4;
    const int tid = threadIdx.x;
    const int wave = tid >> 6, lane = tid & 63, il = lane & 15, quad = lane >> 4;
    const int qbase = qt*128 + wave*32;
    const int kbase = split*1024;
    const int swz = il & 7;

    const unsigned short* Qh = Qb + (size_t)(n*NHEAD + h)*S_LEN*DHEAD;
    const unsigned short* Kh = Kfr + (size_t)(n*NHEAD + h)*S_LEN*DHEAD + (size_t)kbase*DHEAD + lane*8;
    const unsigned short* Vh = Vfr + (size_t)(n*NHEAD + h)*S_LEN*DHEAD + (size_t)kbase*DHEAD + lane*8;
    // fragment-q mask: record (n, kslab, q) of 8 uints; lane reads record(q)+quad*2
    const unsigned* mrow0 = Mf + ((size_t)(n*128 + (kbase >> 4))*2048 + qbase + il)*8 + quad*2;
    const unsigned* mrow1 = mrow0 + 16*8;

    bf16x8 Qf[2][2];   // B-operand: n=il -> q row, k=quad*8+j -> d
#pragma unroll
    for (int rt = 0; rt < 2; rt++)
#pragma unroll
        for (int ks = 0; ks < 2; ks++)
            Qf[rt][ks] = *(const bf16x8*)(Qh + (qbase + rt*16 + il)*DHEAD + ks*32 + quad*8);

    f32x4 acc[2][4], accL[2];
#pragma unroll
    for (int rt = 0; rt < 2; rt++){
        accL[rt] = (f32x4){0.f,0.f,0.f,0.f};
#pragma unroll
        for (int j = 0; j < 4; j++) acc[rt][j] = (f32x4){0.f,0.f,0.f,0.f};
    }
    const short onev = 0x3F80;   // bf16 1.0
    const bf16x8 onesb = {onev,onev,onev,onev,onev,onev,onev,onev};

    unsigned short* Pw = Pt[wave];
    const int pw_base = (il << 6) + ((quad & 1) << 2);
    const int pw_qhi  = quad >> 1;
    const int pr_base = (il << 6);

    for (int kb = 0; kb < 1024; kb += 64){
        const unsigned short* Kt = Kh + kb*64;
        const unsigned short* Vt = Vh + kb*64;

        // QK^T per 16-k slab t: E^T = K.Q^T; C: col=il -> q, row=quad*4+r -> k
#pragma unroll
        for (int t = 0; t < 4; t++){
            bf16x8 kf0 = *(const bf16x8*)(Kt + t*1024);
            bf16x8 kf1 = *(const bf16x8*)(Kt + t*1024 + 512);
            f32x4 z0 = (f32x4){0.f,0.f,0.f,0.f};
            z0 = __builtin_amdgcn_mfma_f32_16x16x32_bf16(kf0, Qf[0][0], z0, 0, 0, 0);
            f32x4 e0 = __builtin_amdgcn_mfma_f32_16x16x32_bf16(kf1, Qf[0][1], z0, 0, 0, 0);
            f32x4 z1 = (f32x4){0.f,0.f,0.f,0.f};
            z1 = __builtin_amdgcn_mfma_f32_16x16x32_bf16(kf0, Qf[1][0], z1, 0, 0, 0);
            f32x4 e1 = __builtin_amdgcn_mfma_f32_16x16x32_bf16(kf1, Qf[1][1], z1, 0, 0, 0);
            size_t soff = (size_t)((kb >> 4) + t) * 16384;   // slab stride = 2048 records * 8
            uint2 mw0 = *(const uint2*)(mrow0 + soff);
            uint2 mw1 = *(const uint2*)(mrow1 + soff);
            uint2 pk0, pk1;
            pk0.x = pk2bf(fast_exp2(e0[0]), fast_exp2(e0[1])) & mw0.x;
            pk0.y = pk2bf(fast_exp2(e0[2]), fast_exp2(e0[3])) & mw0.y;
            pk1.x = pk2bf(fast_exp2(e1[0]), fast_exp2(e1[1])) & mw1.x;
            pk1.y = pk2bf(fast_exp2(e1[2]), fast_exp2(e1[3])) & mw1.y;
            int blk = ((t*2 + pw_qhi) ^ swz) << 3;
            *(uint2*)&Pw[pw_base + blk]             = pk0;
            *(uint2*)&Pw[(16 << 6) + pw_base + blk] = pk1;
        }
        // PV: O += P.V ; l += P.1
#pragma unroll
        for (int kk = 0; kk < 2; kk++){
            int rblk = (((kk*4 + quad) ^ swz) << 3);
            bf16x8 Pa0 = *(const bf16x8*)&Pw[pr_base + rblk];
            bf16x8 Pa1 = *(const bf16x8*)&Pw[(16 << 6) + pr_base + rblk];
            accL[0] = __builtin_amdgcn_mfma_f32_16x16x32_bf16(Pa0, onesb, accL[0], 0, 0, 0);
            accL[1] = __builtin_amdgcn_mfma_f32_16x16x32_bf16(Pa1, onesb, accL[1], 0, 0, 0);
#pragma unroll
            for (int dt = 0; dt < 4; dt++){
                bf16x8 Vf = *(const bf16x8*)(Vt + (dt*2 + kk)*512);
                acc[0][dt] = __builtin_amdgcn_mfma_f32_16x16x32_bf16(Pa0, Vf, acc[0][dt], 0, 0, 0);
                acc[1][dt] = __builtin_amdgcn_mfma_f32_16x16x32_bf16(Pa1, Vf, acc[1][dt], 0, 0, 0);
            }
        }
        // no barrier: P buffers are wave-private
    }

    // epilogue: accumulate unnormalized O partial + l partial (atomic; 2 splits commute)
#pragma unroll
    for (int rt = 0; rt < 2; rt++){
#pragma unroll
        for (int dt = 0; dt < 4; dt++)
#pragma unroll
            for (int r = 0; r < 4; r++){
                size_t row = (size_t)(n*S_LEN + qbase + rt*16 + quad*4 + r);
                atomicAdd(&Op[row*EMB + h*DHEAD + dt*16 + il], acc[rt][dt][r]);
            }
        if (il == 0){
#pragma unroll
            for (int r = 0; r < 4; r++)
                atomicAdd(&Lp[(n*NHEAD + h)*S_LEN + qbase + rt*16 + quad*4 + r], accL[rt][r]);
        }
    }
}

// ---------------- normalize -> bf16 AttO [N*S, EMB] ----------------
__global__ void merge_norm(const float* __restrict__ Op, const float* __restrict__ Lp,
                           unsigned short* __restrict__ AttO){
    int idx = blockIdx.x*256 + threadIdx.x;       // 4096 rows x 256 float4-chunks
    int row = idx >> 8, c4 = (idx & 255)*4;
    int n = row >> 11, q = row & (S_LEN-1), h = c4 >> 6;
    float4 o = *(const float4*)(Op + (size_t)row*EMB + c4);
    float l = Lp[(n*NHEAD + h)*S_LEN + q];
    float inv = fast_rcp(l);
    uint2 p;
    p.x = pk2bf(o.x*inv, o.y*inv);
    p.y = pk2bf(o.z*inv, o.w*inv);
    *(uint2*)(AttO + (size_t)row*EMB + c4) = p;
}

// ---------------- output GEMM: out[4096,1024] = A.W^T + b, 128x128 tiles ----------------
// grid (8,32) = 256 blocks. bf16 A: panel re-read 8x = 64 MB (vs fp32-fused 256 MB,
// which was L3-BW-bound at ~100+ us in every prior round). Swizzled LDS, reg prefetch.
__global__ __launch_bounds__(256, 2) void gemm_out(
    const unsigned short* __restrict__ A, const unsigned short* __restrict__ W,
    const float* __restrict__ bias, float* __restrict__ out){
    __shared__ unsigned short At[128*64];
    __shared__ unsigned short Wt[128*64];
    const int nb = blockIdx.x, mb = blockIdx.y;
    const int tid = threadIdx.x;
    const int wave = tid >> 6, lane = tid & 63, il = lane & 15, quad = lane >> 4;
    const int wm = wave & 1, wn = wave >> 1;
    const int mbase = mb*128, nbase = nb*128;
    const int arow = tid >> 3, ab8 = tid & 7;
    const int sblk = (ab8 ^ (arow & 7)) << 3;

    f32x4 acc[4][4];
#pragma unroll
    for (int i = 0; i < 4; i++)
#pragma unroll
        for (int j = 0; j < 4; j++) acc[i][j] = (f32x4){0.f,0.f,0.f,0.f};

    uint4 apre[4], wpre[4];
#pragma unroll
    for (int j = 0; j < 4; j++){
        apre[j] = *(const uint4*)(A + (size_t)(mbase + arow + j*32)*EMB + ab8*8);
        wpre[j] = *(const uint4*)(W + (size_t)(nbase + arow + j*32)*EMB + ab8*8);
    }

    for (int kb = 0; kb < EMB; kb += 64){
#pragma unroll
        for (int j = 0; j < 4; j++){
            *(uint4*)&At[((arow + j*32) << 6) + sblk] = apre[j];
            *(uint4*)&Wt[((arow + j*32) << 6) + sblk] = wpre[j];
        }
        __syncthreads();
        if (kb + 64 < EMB){
#pragma unroll
            for (int j = 0; j < 4; j++){
                apre[j] = *(const uint4*)(A + (size_t)(mbase + arow + j*32)*EMB + kb + 64 + ab8*8);
                wpre[j] = *(const uint4*)(W + (size_t)(nbase + arow + j*32)*EMB + kb + 64 + ab8*8);
            }
        }
#pragma unroll
        for (int ks = 0; ks < 2; ks++){
            int fblk = ((ks*4 + quad) ^ (il & 7)) << 3;
            bf16x8 Af[4], Wf[4];
#pragma unroll
            for (int mt = 0; mt < 4; mt++)
                Af[mt] = *(const bf16x8*)(&At[((wm*64 + mt*16 + il) << 6) + fblk]);
#pragma unroll
            for (int nt = 0; nt < 4; nt++)
                Wf[nt] = *(const bf16x8*)(&Wt[((wn*64 + nt*16 + il) << 6) + fblk]);
#pragma unroll
            for (int mt = 0; mt < 4; mt++)
#pragma unroll
                for (int nt = 0; nt < 4; nt++)
                    acc[mt][nt] = __builtin_amdgcn_mfma_f32_16x16x32_bf16(Af[mt], Wf[nt], acc[mt][nt], 0, 0, 0);
        }
        __syncthreads();
    }
    float bb[4];
#pragma unroll
    for (int nt = 0; nt < 4; nt++) bb[nt] = bias[nbase + wn*64 + nt*16 + il];
#pragma unroll
    for (int mt = 0; mt < 4; mt++)
#pragma unroll
        for (int nt = 0; nt < 4; nt++)
#pragma unroll
            for (int r = 0; r < 4; r++){
                int row = mbase + wm*64 + mt*16 + quad*4 + r;
                int col = nbase + wn*64 + nt*16 + il;
                out[(size_t)row*EMB + col] = acc[mt][nt][r] + bb[nt];
            }
}

extern "C" void kernel_launch(void* const* d_in, const int* in_sizes, int n_in,
                              void* d_out, int out_size, void* d_ws, size_t ws_size,
                              hipStream_t stream){
    const float* values = (const float*)d_in[0];
    const float* keys   = (const float*)d_in[1];
    const float* query  = (const float*)d_in[2];
    const int*   mask   = (const int*)d_in[3];
    const float* W_fc   = (const float*)d_in[4];
    const float* b_fc   = (const float*)d_in[5];
    float* out = (float*)d_out;

    char* ws = (char*)d_ws;
    unsigned short* Qb  = (unsigned short*)(ws);                        // 8 MB
    unsigned short* Kfr = (unsigned short*)(ws + (8ull  << 20));        // 8 MB (fragment order)
    unsigned short* Vfr = (unsigned short*)(ws + (16ull << 20));        // 8 MB (fragment order)
    unsigned short* Wb  = (unsigned short*)(ws + (24ull << 20));        // 2 MB
    unsigned*       Mf  = (unsigned*)      (ws + (26ull << 20));        // 16 MB (fragment-q masks)
    float*          Opf = (float*)         (ws + (42ull << 20));        // 16 MB (fp32 O accum)
    float*          Lpf = (float*)         (ws + (58ull << 20));        // 256 KB
    unsigned short* AttO= (unsigned short*)(ws + (58ull << 20) + (512ull << 10)); // 8 MB -> 66.5 MB

    prep_all  <<<15376, 256, 0, stream>>>(query, keys, values, mask, W_fc,
                                          Qb, Kfr, Vfr, Wb, Mf, (float4*)Opf);
    flash_attn<<<dim3(16, 32, 2), 256, 0, stream>>>(Qb, Kfr, Vfr, Mf, Opf, Lpf);
    merge_norm<<<4096, 256, 0, stream>>>(Opf, Lpf, AttO);
    gemm_out  <<<dim3(8, 32), 256, 0, stream>>>(AttO, Wb, b_fc, out);
}

// Round 8
// 285.971 us; speedup vs baseline: 1.0346x; 1.0346x over previous
//
#include <hip/hip_runtime.h>
#include <cmath>

#define S_LEN 2048
#define EMB   1024
#define NHEAD 16
#define DHEAD 64

typedef __attribute__((ext_vector_type(8))) short bf16x8;
typedef __attribute__((ext_vector_type(4))) float f32x4;

__device__ __forceinline__ unsigned short f2bf(float f){
    union { float f; unsigned u; } v; v.f = f;
    unsigned r = v.u + 0x7fffu + ((v.u >> 16) & 1u);
    return (unsigned short)(r >> 16);
}

__device__ __forceinline__ unsigned pk2bf(float a, float b){
#if __has_builtin(__builtin_amdgcn_cvt_pk_bf16_f32)
    typedef __attribute__((ext_vector_type(2))) __bf16 bf2;
    bf2 r = __builtin_amdgcn_cvt_pk_bf16_f32(a, b);
    return *(unsigned*)&r;
#else
    return (unsigned)f2bf(a) | ((unsigned)f2bf(b) << 16);
#endif
}

__device__ __forceinline__ float fast_exp2(float x){
#if __has_builtin(__builtin_amdgcn_exp2f)
    return __builtin_amdgcn_exp2f(x);
#else
    return exp2f(x);
#endif
}

__device__ __forceinline__ float fast_rcp(float x){
#if __has_builtin(__builtin_amdgcn_rcpf)
    return __builtin_amdgcn_rcpf(x);
#else
    return 1.0f / x;
#endif
}

// ---------------- fused prep: range-dispatched over blockIdx.x ----------------
// [0,4096):       Q -> bf16 [N,H,S,D] (prescaled exp2-domain); K -> FRAGMENT order
// [4096,5120):    V -> FRAGMENT order
// [5120,6144):    W -> bf16
// [6144,14336):   mask -> fragment-q pair-masks, COALESCED STORES (thread = one Mf uint2,
//                 int4 reads land in 64B segments; r7 had the scatter on the store side)
// [14336,18432):  out = bias broadcast (gemm atomically accumulates on top)
__global__ void prep_all(const float* __restrict__ q, const float* __restrict__ k,
                         const float* __restrict__ v, const int* __restrict__ mask,
                         const float* __restrict__ W, const float* __restrict__ bias,
                         unsigned short* __restrict__ Qb, unsigned short* __restrict__ Kb,
                         unsigned short* __restrict__ Vt, unsigned short* __restrict__ Wb,
                         unsigned* __restrict__ Mf, float4* __restrict__ outp){
    __shared__ unsigned short tile[64*68];
    const int b = blockIdx.x, tid = threadIdx.x;
    if (b < 4096){
        const float SC = 0.045084220027780106f;   // log2(e)/32
        int base = (b*256 + tid) * 4;
        int e = base & (EMB - 1);
        int s = (base >> 10) & (S_LEN - 1);
        int n = base >> 21;
        int h = e >> 6, d = e & 63;
        float4 qv = *(const float4*)(q + base);
        float4 kv = *(const float4*)(k + base);
        uint2 qp, kp;
        qp.x = pk2bf(qv.x*SC, qv.y*SC);
        qp.y = pk2bf(qv.z*SC, qv.w*SC);
        kp.x = pk2bf(kv.x, kv.y);
        kp.y = pk2bf(kv.z, kv.w);
        *(uint2*)(Qb + ((size_t)((n*NHEAD + h)*S_LEN + s))*DHEAD + d) = qp;
        int slab = s >> 4, sil = s & 15;
        int ks = d >> 5, qd = (d >> 3) & 3, j = d & 7;
        size_t koff = ((size_t)((n*NHEAD + h)*128 + slab))*1024 + ks*512 + (qd*16 + sil)*8 + j;
        *(uint2*)(Kb + koff) = kp;
    } else if (b < 5120){
        int idx = b - 4096;
        int st = idx & 31, h = (idx >> 5) & 15, n = idx >> 9;
        int sbase = st * 64;
#pragma unroll
        for (int i = 0; i < 4; i++){
            int c = tid + i*256;
            int srow = c >> 4, c4 = (c & 15) * 4;
            float4 x = *(const float4*)(v + (n*S_LEN + sbase + srow)*EMB + h*DHEAD + c4);
            uint2 p;
            p.x = pk2bf(x.x, x.y);
            p.y = pk2bf(x.z, x.w);
            *(uint2*)&tile[srow*68 + c4] = p;
        }
        __syncthreads();
        unsigned short* Vh = Vt + ((size_t)((n*NHEAD + h)*32 + st))*4096;
#pragma unroll
        for (int i = 0; i < 2; i++){
            int c = tid + i*256;            // 0..511 chunks of 16B
            int ln = c & 63, dk = c >> 6;   // dk = dt*2+kk
            int dt = dk >> 1, kk = dk & 1;
            int q2 = ln >> 4, i2 = ln & 15;
            int colb = dt*16 + i2;
            int rowb = kk*32 + q2*8;
            unsigned u0 = (unsigned)tile[(rowb+0)*68 + colb] | ((unsigned)tile[(rowb+1)*68 + colb] << 16);
            unsigned u1 = (unsigned)tile[(rowb+2)*68 + colb] | ((unsigned)tile[(rowb+3)*68 + colb] << 16);
            unsigned u2 = (unsigned)tile[(rowb+4)*68 + colb] | ((unsigned)tile[(rowb+5)*68 + colb] << 16);
            unsigned u3 = (unsigned)tile[(rowb+6)*68 + colb] | ((unsigned)tile[(rowb+7)*68 + colb] << 16);
            uint4 pk; pk.x = u0; pk.y = u1; pk.z = u2; pk.w = u3;
            *(uint4*)(Vh + c*8) = pk;
        }
    } else if (b < 6144){
        int base = ((b - 5120)*256 + tid) * 4;
        float4 x = *(const float4*)(W + base);
        uint2 p;
        p.x = pk2bf(x.x, x.y);
        p.y = pk2bf(x.z, x.w);
        *(uint2*)(Wb + base) = p;
    } else if (b < 14336){
        int w = (b - 6144)*256 + tid;     // Mf uint2 linear index (coalesced store)
        int c    =  w        & 3;         // k-quad within slab (4 k-values)
        int qq   = (w >> 2)  & 2047;
        int slab = (w >> 13) & 127;
        int nn   =  w >> 20;
        int4 m = ((const int4*)mask)[(nn*2048 + qq)*512 + slab*4 + c];
        uint2 o;
        o.x = (m.x ? 0xFFFFu : 0u) | (m.y ? 0xFFFF0000u : 0u);
        o.y = (m.z ? 0xFFFFu : 0u) | (m.w ? 0xFFFF0000u : 0u);
        *(uint2*)(Mf + (size_t)w*2) = o;
    } else {
        int gid = (b - 14336)*256 + tid;  // float4 units over out[4096,1024]
        int col4 = (gid & 255)*4;
        outp[gid] = *(const float4*)(bias + col4);
    }
}

// ---------------- flash attention v6: block-internal split-K, zero global plumbing ----------
// grid (qt=32, h=16, n=2) = 1024 blocks (4/CU), block 256 (4 waves).
// Waves (wq, kh): wq = q-subtile (32 rows), kh = k-half. Loop identical to r7 (the 90 us
// kernel). Epilogue: kh=1 waves publish O/l partials in LDS; kh=0 waves combine, normalize,
// and write bf16 AttO directly. Deletes: Op zeroing, 67 MB fp32 atomic RMW, merge kernel.
__global__ __launch_bounds__(256, 4) void flash_attn(
    const unsigned short* __restrict__ Qb, const unsigned short* __restrict__ Kfr,
    const unsigned short* __restrict__ Vfr, const unsigned* __restrict__ Mf,
    unsigned short* __restrict__ AttO){
    __shared__ unsigned short Pt[4][32*64];
    __shared__ float Xo[2][32*64];
    __shared__ float Xl[2][32];

    const int n = blockIdx.z, qt = blockIdx.x, h = blockIdx.y;
    const int tid = threadIdx.x;
    const int wave = tid >> 6, lane = tid & 63, il = lane & 15, quad = lane >> 4;
    const int wq = wave & 1, kh = wave >> 1;
    const int qbase = qt*64 + wq*32;
    const int kbase = kh*1024;
    const int swz = il & 7;

    const unsigned short* Qh = Qb + (size_t)(n*NHEAD + h)*S_LEN*DHEAD;
    const unsigned short* Kh = Kfr + (size_t)(n*NHEAD + h)*S_LEN*DHEAD + (size_t)kbase*DHEAD + lane*8;
    const unsigned short* Vh = Vfr + (size_t)(n*NHEAD + h)*S_LEN*DHEAD + (size_t)kbase*DHEAD + lane*8;
    const unsigned* mrow0 = Mf + ((size_t)(n*128 + (kbase >> 4))*2048 + qbase + il)*8 + quad*2;
    const unsigned* mrow1 = mrow0 + 16*8;

    bf16x8 Qf[2][2];   // B-operand: n=il -> q row, k=quad*8+j -> d
#pragma unroll
    for (int rt = 0; rt < 2; rt++)
#pragma unroll
        for (int ks = 0; ks < 2; ks++)
            Qf[rt][ks] = *(const bf16x8*)(Qh + (qbase + rt*16 + il)*DHEAD + ks*32 + quad*8);

    f32x4 acc[2][4], accL[2];
#pragma unroll
    for (int rt = 0; rt < 2; rt++){
        accL[rt] = (f32x4){0.f,0.f,0.f,0.f};
#pragma unroll
        for (int j = 0; j < 4; j++) acc[rt][j] = (f32x4){0.f,0.f,0.f,0.f};
    }
    const short onev = 0x3F80;   // bf16 1.0
    const bf16x8 onesb = {onev,onev,onev,onev,onev,onev,onev,onev};

    unsigned short* Pw = Pt[wave];
    const int pw_base = (il << 6) + ((quad & 1) << 2);
    const int pw_qhi  = quad >> 1;
    const int pr_base = (il << 6);

    for (int kb = 0; kb < 1024; kb += 64){
        const unsigned short* Kt = Kh + kb*64;
        const unsigned short* Vt = Vh + kb*64;

        // QK^T per 16-k slab t: E^T = K.Q^T; C: col=il -> q, row=quad*4+r -> k
#pragma unroll
        for (int t = 0; t < 4; t++){
            bf16x8 kf0 = *(const bf16x8*)(Kt + t*1024);
            bf16x8 kf1 = *(const bf16x8*)(Kt + t*1024 + 512);
            f32x4 z0 = (f32x4){0.f,0.f,0.f,0.f};
            z0 = __builtin_amdgcn_mfma_f32_16x16x32_bf16(kf0, Qf[0][0], z0, 0, 0, 0);
            f32x4 e0 = __builtin_amdgcn_mfma_f32_16x16x32_bf16(kf1, Qf[0][1], z0, 0, 0, 0);
            f32x4 z1 = (f32x4){0.f,0.f,0.f,0.f};
            z1 = __builtin_amdgcn_mfma_f32_16x16x32_bf16(kf0, Qf[1][0], z1, 0, 0, 0);
            f32x4 e1 = __builtin_amdgcn_mfma_f32_16x16x32_bf16(kf1, Qf[1][1], z1, 0, 0, 0);
            size_t soff = (size_t)((kb >> 4) + t) * 16384;   // slab stride = 2048 records * 8
            uint2 mw0 = *(const uint2*)(mrow0 + soff);
            uint2 mw1 = *(const uint2*)(mrow1 + soff);
            uint2 pk0, pk1;
            pk0.x = pk2bf(fast_exp2(e0[0]), fast_exp2(e0[1])) & mw0.x;
            pk0.y = pk2bf(fast_exp2(e0[2]), fast_exp2(e0[3])) & mw0.y;
            pk1.x = pk2bf(fast_exp2(e1[0]), fast_exp2(e1[1])) & mw1.x;
            pk1.y = pk2bf(fast_exp2(e1[2]), fast_exp2(e1[3])) & mw1.y;
            int blk = ((t*2 + pw_qhi) ^ swz) << 3;
            *(uint2*)&Pw[pw_base + blk]             = pk0;
            *(uint2*)&Pw[(16 << 6) + pw_base + blk] = pk1;
        }
        // PV: O += P.V ; l += P.1
#pragma unroll
        for (int kk = 0; kk < 2; kk++){
            int rblk = (((kk*4 + quad) ^ swz) << 3);
            bf16x8 Pa0 = *(const bf16x8*)&Pw[pr_base + rblk];
            bf16x8 Pa1 = *(const bf16x8*)&Pw[(16 << 6) + pr_base + rblk];
            accL[0] = __builtin_amdgcn_mfma_f32_16x16x32_bf16(Pa0, onesb, accL[0], 0, 0, 0);
            accL[1] = __builtin_amdgcn_mfma_f32_16x16x32_bf16(Pa1, onesb, accL[1], 0, 0, 0);
#pragma unroll
            for (int dt = 0; dt < 4; dt++){
                bf16x8 Vf = *(const bf16x8*)(Vt + (dt*2 + kk)*512);
                acc[0][dt] = __builtin_amdgcn_mfma_f32_16x16x32_bf16(Pa0, Vf, acc[0][dt], 0, 0, 0);
                acc[1][dt] = __builtin_amdgcn_mfma_f32_16x16x32_bf16(Pa1, Vf, acc[1][dt], 0, 0, 0);
            }
        }
        // no barrier in-loop: P buffers are wave-private
    }

    // epilogue: combine the two k-halves in LDS, normalize, write bf16
    if (kh == 1){
#pragma unroll
        for (int rt = 0; rt < 2; rt++){
#pragma unroll
            for (int dt = 0; dt < 4; dt++)
#pragma unroll
                for (int r = 0; r < 4; r++)
                    Xo[wq][(rt*16 + quad*4 + r)*64 + dt*16 + il] = acc[rt][dt][r];
            if (il == 0){
#pragma unroll
                for (int r = 0; r < 4; r++)
                    Xl[wq][rt*16 + quad*4 + r] = accL[rt][r];
            }
        }
    }
    __syncthreads();
    if (kh == 0){
#pragma unroll
        for (int rt = 0; rt < 2; rt++)
#pragma unroll
            for (int r = 0; r < 4; r++){
                int q32 = rt*16 + quad*4 + r;
                float lt = accL[rt][r] + Xl[wq][q32];
                float inv = fast_rcp(lt);
                size_t row = (size_t)(n*S_LEN + qbase + q32);
#pragma unroll
                for (int dt = 0; dt < 4; dt++){
                    float o = acc[rt][dt][r] + Xo[wq][q32*64 + dt*16 + il];
                    AttO[row*EMB + h*DHEAD + dt*16 + il] = f2bf(o*inv);
                }
            }
    }
}

// ---------------- output GEMM: out += A.W^T, 128x128 tiles, split-K x2 ----------------
// grid (8, 32, 2) = 512 blocks (2/CU, 2x r7's block count at the same tile size).
// out pre-initialized with bias in prep; the two K-split blocks atomicAdd fp32 (commuting,
// ~1ulp nondeterminism << threshold). Swizzled LDS, register prefetch.
__global__ __launch_bounds__(256, 2) void gemm_out(
    const unsigned short* __restrict__ A, const unsigned short* __restrict__ W,
    float* __restrict__ out){
    __shared__ unsigned short At[128*64];
    __shared__ unsigned short Wt[128*64];
    const int nb = blockIdx.x, mb = blockIdx.y, split = blockIdx.z;
    const int tid = threadIdx.x;
    const int wave = tid >> 6, lane = tid & 63, il = lane & 15, quad = lane >> 4;
    const int wm = wave & 1, wn = wave >> 1;
    const int mbase = mb*128, nbase = nb*128;
    const int kb0 = split*512;
    const int arow = tid >> 3, ab8 = tid & 7;
    const int sblk = (ab8 ^ (arow & 7)) << 3;

    f32x4 acc[4][4];
#pragma unroll
    for (int i = 0; i < 4; i++)
#pragma unroll
        for (int j = 0; j < 4; j++) acc[i][j] = (f32x4){0.f,0.f,0.f,0.f};

    uint4 apre[4], wpre[4];
#pragma unroll
    for (int j = 0; j < 4; j++){
        apre[j] = *(const uint4*)(A + (size_t)(mbase + arow + j*32)*EMB + kb0 + ab8*8);
        wpre[j] = *(const uint4*)(W + (size_t)(nbase + arow + j*32)*EMB + kb0 + ab8*8);
    }

    for (int kb = kb0; kb < kb0 + 512; kb += 64){
#pragma unroll
        for (int j = 0; j < 4; j++){
            *(uint4*)&At[((arow + j*32) << 6) + sblk] = apre[j];
            *(uint4*)&Wt[((arow + j*32) << 6) + sblk] = wpre[j];
        }
        __syncthreads();
        if (kb + 64 < kb0 + 512){
#pragma unroll
            for (int j = 0; j < 4; j++){
                apre[j] = *(const uint4*)(A + (size_t)(mbase + arow + j*32)*EMB + kb + 64 + ab8*8);
                wpre[j] = *(const uint4*)(W + (size_t)(nbase + arow + j*32)*EMB + kb + 64 + ab8*8);
            }
        }
#pragma unroll
        for (int ks = 0; ks < 2; ks++){
            int fblk = ((ks*4 + quad) ^ (il & 7)) << 3;
            bf16x8 Af[4], Wf[4];
#pragma unroll
            for (int mt = 0; mt < 4; mt++)
                Af[mt] = *(const bf16x8*)(&At[((wm*64 + mt*16 + il) << 6) + fblk]);
#pragma unroll
            for (int nt = 0; nt < 4; nt++)
                Wf[nt] = *(const bf16x8*)(&Wt[((wn*64 + nt*16 + il) << 6) + fblk]);
#pragma unroll
            for (int mt = 0; mt < 4; mt++)
#pragma unroll
                for (int nt = 0; nt < 4; nt++)
                    acc[mt][nt] = __builtin_amdgcn_mfma_f32_16x16x32_bf16(Af[mt], Wf[nt], acc[mt][nt], 0, 0, 0);
        }
        __syncthreads();
    }
#pragma unroll
    for (int mt = 0; mt < 4; mt++)
#pragma unroll
        for (int nt = 0; nt < 4; nt++)
#pragma unroll
            for (int r = 0; r < 4; r++){
                int row = mbase + wm*64 + mt*16 + quad*4 + r;
                int col = nbase + wn*64 + nt*16 + il;
                atomicAdd(&out[(size_t)row*EMB + col], acc[mt][nt][r]);
            }
}

extern "C" void kernel_launch(void* const* d_in, const int* in_sizes, int n_in,
                              void* d_out, int out_size, void* d_ws, size_t ws_size,
                              hipStream_t stream){
    const float* values = (const float*)d_in[0];
    const float* keys   = (const float*)d_in[1];
    const float* query  = (const float*)d_in[2];
    const int*   mask   = (const int*)d_in[3];
    const float* W_fc   = (const float*)d_in[4];
    const float* b_fc   = (const float*)d_in[5];
    float* out = (float*)d_out;

    char* ws = (char*)d_ws;
    unsigned short* Qb  = (unsigned short*)(ws);                        // 8 MB
    unsigned short* Kfr = (unsigned short*)(ws + (8ull  << 20));        // 8 MB (fragment order)
    unsigned short* Vfr = (unsigned short*)(ws + (16ull << 20));        // 8 MB (fragment order)
    unsigned short* Wb  = (unsigned short*)(ws + (24ull << 20));        // 2 MB
    unsigned*       Mf  = (unsigned*)      (ws + (26ull << 20));        // 16 MB (fragment-q masks)
    unsigned short* AttO= (unsigned short*)(ws + (42ull << 20));        // 8 MB -> 50 MB total

    prep_all  <<<18432, 256, 0, stream>>>(query, keys, values, mask, W_fc, b_fc,
                                          Qb, Kfr, Vfr, Wb, Mf, (float4*)out);
    flash_attn<<<dim3(32, 16, 2), 256, 0, stream>>>(Qb, Kfr, Vfr, Mf, AttO);
    gemm_out  <<<dim3(8, 32, 2), 256, 0, stream>>>(AttO, Wb, out);
}